// Round 1
// baseline (1174.978 us; speedup 1.0000x reference)
//
#include <hip/hip_runtime.h>

typedef __bf16 bf16_t;
typedef bf16_t bf16x8 __attribute__((ext_vector_type(8)));
typedef float f32x4 __attribute__((ext_vector_type(4)));

#define B_    8
#define H_    16
#define S_    16
#define D_    2048
#define HD    128
#define CL    4096
#define TL    4112
#define NCH   17        // 16 cache chunks + 1 "new keys" chunk
#define CHUNK 256
#define PSTRIDE 2080    // per (bh,chunk) partial: m[16], l[16], O[16][128]
#define SCALE 0.08838834764831845f  // 1/sqrt(128)

__device__ inline f32x4 mfma16(bf16x8 a, bf16x8 b, f32x4 c) {
  return __builtin_amdgcn_mfma_f32_16x16x32_bf16(a, b, c, 0, 0, 0);
}

__device__ inline bf16x8 cvt8(f32x4 a, f32x4 b) {
  bf16x8 r;
  r[0] = (bf16_t)a[0]; r[1] = (bf16_t)a[1]; r[2] = (bf16_t)a[2]; r[3] = (bf16_t)a[3];
  r[4] = (bf16_t)b[0]; r[5] = (bf16_t)b[1]; r[6] = (bf16_t)b[2]; r[7] = (bf16_t)b[3];
  return r;
}

// ---------------------------------------------------------------------------
// GEMM: A[128 x 2048] @ W[2048 x N] + bias.
// MODE 1 (QKV): N=6144, A=x (fp32). cols 0..2047 -> q_ws (bf16);
//               2048..4095 -> kh tail (fp32); 4096..6143 -> vh tail (fp32).
// MODE 0 (proj): N=2048, A=ctx (bf16). -> out (fp32).
// 256 thr = 4 waves; block tile 64 rows x 64 cols; wave tile 16x64.
// Double-buffered LDS + 2-deep register prefetch: one barrier per 32-k step,
// W loads always >=1 full iteration in flight. Grid is linear; blocks bid and
// bid+8 share a W column tile (same XCD under round-robin -> L2 hit).
// ---------------------------------------------------------------------------
template <bool ABF16, int MODE>
__global__ __launch_bounds__(256)
void gemm_k(const void* __restrict__ Ap_, const float* __restrict__ W,
            const float* __restrict__ bias, bf16_t* __restrict__ qout,
            float* __restrict__ khout, float* __restrict__ vhout,
            float* __restrict__ outp, int N) {
  __shared__ __align__(16) bf16_t Wt[2][64][40];  // [buf][n][k], 80 B rows
  const int tid = threadIdx.x;
  const int w = tid >> 6, lane = tid & 63, q4 = lane >> 4, li = lane & 15;
  const int bid = blockIdx.x;
  const int colb = (bid >> 4) * 8 + (bid & 7);   // column tile
  const int rowg = (bid >> 3) & 1;               // row group; partner is bid^8
  const int n0 = colb * 64;
  const int row = rowg * 64 + w * 16 + li;

  const int kk_a = tid >> 4, nn4 = (tid & 15) * 4;  // staging coords
  const long strideW = (long)32 * N;
  const float* Wpa = W + (long)kk_a * N + n0 + nn4;  // tile-row kk_a
  const float* Wpb = Wpa + (long)16 * N;             // tile-row kk_a+16

  f32x4 acc[4];
#pragma unroll
  for (int i = 0; i < 4; ++i) acc[i] = (f32x4){0.f, 0.f, 0.f, 0.f};

  const bf16_t* Ab = (const bf16_t*)Ap_ + (long)row * D_;
  const float* Af = (const float*)Ap_ + (long)row * D_;

  // W prefetch: tile0 -> a-regs (staged immediately), tile1 -> b-regs
  f32x4 wa0 = *(const f32x4*)Wpa;
  f32x4 wa1 = *(const f32x4*)Wpb;
  f32x4 wb0 = *(const f32x4*)(Wpa + strideW);
  f32x4 wb1 = *(const f32x4*)(Wpb + strideW);
  // A prefetch for t=0
  bf16x8 aCb = {};
  f32x4 aC0 = {0.f, 0.f, 0.f, 0.f}, aC1 = {0.f, 0.f, 0.f, 0.f};
  if (ABF16) aCb = *(const bf16x8*)(Ab + q4 * 8);
  else { aC0 = *(const f32x4*)(Af + q4 * 8); aC1 = *(const f32x4*)(Af + q4 * 8 + 4); }

#pragma unroll
  for (int i = 0; i < 4; ++i) {
    Wt[0][nn4 + i][kk_a] = (bf16_t)wa0[i];
    Wt[0][nn4 + i][kk_a + 16] = (bf16_t)wa1[i];
  }
  __syncthreads();

#pragma unroll 2
  for (int t = 0; t < 64; ++t) {
    const int cur = t & 1;
    const int k0 = t * 32;
    // prefetch W tile t+2 into n-regs
    f32x4 na0 = {0.f, 0.f, 0.f, 0.f}, na1 = {0.f, 0.f, 0.f, 0.f};
    if (t < 62) {
      na0 = *(const f32x4*)(Wpa + (long)(t + 2) * strideW);
      na1 = *(const f32x4*)(Wpb + (long)(t + 2) * strideW);
    }
    // prefetch A for t+1
    bf16x8 aNb = {};
    f32x4 aN0 = {0.f, 0.f, 0.f, 0.f}, aN1 = {0.f, 0.f, 0.f, 0.f};
    if (t < 63) {
      if (ABF16) {
        aNb = *(const bf16x8*)(Ab + k0 + 32 + q4 * 8);
      } else {
        const float* ap = Af + k0 + 32 + q4 * 8;
        aN0 = *(const f32x4*)ap;
        aN1 = *(const f32x4*)(ap + 4);
      }
    }
    // compute tile t from Wt[cur]
    bf16x8 av;
    if (ABF16) av = aCb; else av = cvt8(aC0, aC1);
#pragma unroll
    for (int cg = 0; cg < 4; ++cg) {
      bf16x8 bv = *(const bf16x8*)(&Wt[cur][cg * 16 + li][q4 * 8]);
      acc[cg] = mfma16(av, bv, acc[cg]);
    }
    // stage tile t+1 (b-regs) -> other buffer
    if (t < 63) {
#pragma unroll
      for (int i = 0; i < 4; ++i) {
        Wt[cur ^ 1][nn4 + i][kk_a] = (bf16_t)wb0[i];
        Wt[cur ^ 1][nn4 + i][kk_a + 16] = (bf16_t)wb1[i];
      }
    }
    __syncthreads();
    if (t < 62) { wb0 = na0; wb1 = na1; }
    if (t < 63) { if (ABF16) aCb = aNb; else { aC0 = aN0; aC1 = aN1; } }
  }

#pragma unroll
  for (int cg = 0; cg < 4; ++cg) {
#pragma unroll
    for (int r = 0; r < 4; ++r) {
      int rr = rowg * 64 + w * 16 + q4 * 4 + r;  // C row = quad*4+reg
      int n = n0 + cg * 16 + li;                 // C col = lane&15
      float v = acc[cg][r] + bias[n];
      if (MODE == 0) {
        outp[(long)rr * D_ + n] = v;
      } else {
        if (n < D_) {
          qout[(long)rr * D_ + n] = (bf16_t)v;
        } else {
          int nn = n & (D_ - 1);
          int hh = nn >> 7, dd = nn & 127;
          int bb = rr >> 4, ss = rr & 15;
          long off = ((long)(bb * 16 + hh) * TL + CL + ss) * HD + dd;
          if (n < 2 * D_) khout[off] = v; else vhout[off] = v;
        }
      }
    }
  }
}

// ---------------------------------------------------------------------------
// Fused KV-copy + flash attention partials.
// Grid: 128 (b,h) x 17 chunks. Cache chunk = 256 keys (4 subtiles of 64);
// chunk 16 = the 16 new keys from the QKV GEMM. K loads double as the copy
// AND the QK B-frags. V is staged to LDS TRANSPOSED during the copy
// (Vt[d][t], 132-B rows: conflict-free u16 writes, 4B-aligned dword reads
// give the PV B-frags directly) -- no global V re-gather. kh/vh stores are
// non-temporal (pure output stream, keep it out of L2).
// Softmax state m/l lives in registers replicated across (w,li); barriers:
// Bstart (LDS reuse guard), B1 (maxw+Vt ready), B3 (Pbuf+sumw ready).
// ---------------------------------------------------------------------------
__global__ __launch_bounds__(256)
void attn_k(const float* __restrict__ kc, const float* __restrict__ vc,
            const bf16_t* __restrict__ qw, float* __restrict__ khout,
            float* __restrict__ vhout, float* __restrict__ part) {
  const int blk = blockIdx.x;
  const int bh = blk / NCH, ch = blk - bh * NCH;
  const bool is_new = (ch == 16);
  const int tid = threadIdx.x;
  const int w = tid >> 6, lane = tid & 63, q4 = lane >> 4, li = lane & 15;
  const int b = bh >> 4, h = bh & 15;

  __shared__ float maxw[4][16], sumw[4][16];
  __shared__ __align__(16) bf16_t Pbuf[16][72];   // 144 B rows
  __shared__ __align__(16) bf16_t Vt[128][66];    // [d][t], 132 B rows

  // Q A-frags: lane holds Q[s=li][k0 + quad*8 + j]
  bf16x8 Aq[4];
  {
    const bf16_t* qp = qw + (long)(b * 16 + li) * D_ + h * HD + q4 * 8;
#pragma unroll
    for (int i = 0; i < 4; ++i) Aq[i] = *(const bf16x8*)(qp + i * 32);
  }
  f32x4 Ov0 = {0.f, 0.f, 0.f, 0.f}, Ov1 = {0.f, 0.f, 0.f, 0.f};
  float mreg[4], lreg[4];
#pragma unroll
  for (int r = 0; r < 4; ++r) { mreg[r] = -1e30f; lreg[r] = 0.f; }

  const int nst = is_new ? 1 : 4;
  for (int st = 0; st < nst; ++st) {
    const int tl_loc = w * 16 + li;      // key row local to subtile
    const int tloc = st * 64 + tl_loc;   // chunk-local key row

    __syncthreads();  // Bstart: previous subtile's Vt/Pbuf/maxw reads done

    // ---- K load (copy + B-frag), V copy + LDS transpose stage ----
    bf16x8 Bk[4];
    if (!is_new) {
      const float* kp = kc + ((long)bh * CL + ch * CHUNK + tloc) * HD;
      float* kq = khout + ((long)bh * TL + ch * CHUNK + tloc) * HD;
      const float* vp = vc + ((long)bh * CL + ch * CHUNK + tloc) * HD;
      float* vq = vhout + ((long)bh * TL + ch * CHUNK + tloc) * HD;
#pragma unroll
      for (int i = 0; i < 4; ++i) {
        int d0 = i * 32 + q4 * 8;
        f32x4 x0 = *(const f32x4*)(kp + d0);
        f32x4 x1 = *(const f32x4*)(kp + d0 + 4);
        __builtin_nontemporal_store(x0, (f32x4*)(kq + d0));
        __builtin_nontemporal_store(x1, (f32x4*)(kq + d0 + 4));
        Bk[i] = cvt8(x0, x1);
        f32x4 y0 = *(const f32x4*)(vp + d0);
        f32x4 y1 = *(const f32x4*)(vp + d0 + 4);
        __builtin_nontemporal_store(y0, (f32x4*)(vq + d0));
        __builtin_nontemporal_store(y1, (f32x4*)(vq + d0 + 4));
#pragma unroll
        for (int j = 0; j < 4; ++j) {
          Vt[d0 + j][tl_loc] = (bf16_t)y0[j];
          Vt[d0 + 4 + j][tl_loc] = (bf16_t)y1[j];
        }
      }
    } else {
      const bool valid = tloc < S_;
      const float* kp = khout + ((long)bh * TL + CL + tloc) * HD;
#pragma unroll
      for (int i = 0; i < 4; ++i) {
        int d0 = i * 32 + q4 * 8;
        f32x4 x0 = {0.f, 0.f, 0.f, 0.f}, x1 = {0.f, 0.f, 0.f, 0.f};
        if (valid) { x0 = *(const f32x4*)(kp + d0); x1 = *(const f32x4*)(kp + d0 + 4); }
        Bk[i] = cvt8(x0, x1);
      }
    }

    // ---- QK^T (wave's 16-key group), scale, mask ----
    f32x4 c = {0.f, 0.f, 0.f, 0.f};
#pragma unroll
    for (int i = 0; i < 4; ++i) c = mfma16(Aq[i], Bk[i], c);
    float sv[4];
#pragma unroll
    for (int r = 0; r < 4; ++r) {
      float v = c[r] * SCALE;
      if (is_new) {
        int rowq = q4 * 4 + r;
        if (tl_loc > rowq) v = -1e30f;  // causal
      }
      sv[r] = v;
    }

    // ---- wave-local row max over the 16 key-cols (lanes of a quad) ----
#pragma unroll
    for (int r = 0; r < 4; ++r) {
      float v = sv[r];
      v = fmaxf(v, __shfl_xor(v, 1));
      v = fmaxf(v, __shfl_xor(v, 2));
      v = fmaxf(v, __shfl_xor(v, 4));
      v = fmaxf(v, __shfl_xor(v, 8));
      if (li == 0) maxw[w][q4 * 4 + r] = v;
    }
    __syncthreads();  // B1: maxw + Vt ready

    // ---- replicated m-update, P = exp(S-m), Pbuf write ----
    float alpha[4], pv[4];
#pragma unroll
    for (int r = 0; r < 4; ++r) {
      int rowq = q4 * 4 + r;
      float mw = fmaxf(fmaxf(maxw[0][rowq], maxw[1][rowq]),
                       fmaxf(maxw[2][rowq], maxw[3][rowq]));
      float mn = fmaxf(mreg[r], mw);
      alpha[r] = __expf(mreg[r] - mn);
      mreg[r] = mn;
      float p = __expf(sv[r] - mn);
      pv[r] = p;
      Pbuf[rowq][tl_loc] = (bf16_t)p;
    }
#pragma unroll
    for (int r = 0; r < 4; ++r) {
      float u = pv[r];
      u += __shfl_xor(u, 1);
      u += __shfl_xor(u, 2);
      u += __shfl_xor(u, 4);
      u += __shfl_xor(u, 8);
      if (li == 0) sumw[w][q4 * 4 + r] = u;
    }
#pragma unroll
    for (int r = 0; r < 4; ++r) { Ov0[r] *= alpha[r]; Ov1[r] *= alpha[r]; }
    __syncthreads();  // B3: Pbuf + sumw ready

#pragma unroll
    for (int r = 0; r < 4; ++r) {
      int rowq = q4 * 4 + r;
      lreg[r] = lreg[r] * alpha[r] +
                sumw[0][rowq] + sumw[1][rowq] + sumw[2][rowq] + sumw[3][rowq];
    }

    // ---- V B-frags: from Vt (dword reads, 4B-aligned) ----
    bf16x8 Bv[2][2];
    if (!is_new) {
#pragma unroll
      for (int kst = 0; kst < 2; ++kst)
#pragma unroll
        for (int cg = 0; cg < 2; ++cg) {
          int d = w * 32 + cg * 16 + li;
          const unsigned int* vr =
              (const unsigned int*)&Vt[d][kst * 32 + q4 * 8];
          union { unsigned int u[4]; bf16x8 v; } tmp;
          tmp.u[0] = vr[0]; tmp.u[1] = vr[1]; tmp.u[2] = vr[2]; tmp.u[3] = vr[3];
          Bv[kst][cg] = tmp.v;
        }
    } else {
      const float* vb = vhout + ((long)bh * TL + CL) * HD;
#pragma unroll
      for (int kst = 0; kst < 2; ++kst)
#pragma unroll
        for (int cg = 0; cg < 2; ++cg) {
          int d = w * 32 + cg * 16 + li;
#pragma unroll
          for (int j = 0; j < 8; ++j) {
            int tl = kst * 32 + q4 * 8 + j;
            float v = (tl < S_) ? vb[(long)tl * HD + d] : 0.f;
            Bv[kst][cg][j] = (bf16_t)v;
          }
        }
    }

    // ---- PV: A-frags of P from LDS, accumulate O ----
    bf16x8 Ap0 = *(const bf16x8*)(&Pbuf[li][q4 * 8]);
    bf16x8 Ap1 = *(const bf16x8*)(&Pbuf[li][32 + q4 * 8]);
    Ov0 = mfma16(Ap0, Bv[0][0], Ov0);
    Ov0 = mfma16(Ap1, Bv[1][0], Ov0);
    Ov1 = mfma16(Ap0, Bv[0][1], Ov1);
    Ov1 = mfma16(Ap1, Bv[1][1], Ov1);
  }

  // ---- write chunk partial: m[16], l[16], O[16][128] ----
  float* pb = part + ((long)bh * NCH + ch) * PSTRIDE;
  if (w == 0 && li == 0) {
#pragma unroll
    for (int r = 0; r < 4; ++r) {
      pb[q4 * 4 + r] = mreg[r];
      pb[16 + q4 * 4 + r] = lreg[r];
    }
  }
#pragma unroll
  for (int r = 0; r < 4; ++r) {
    int rowq = q4 * 4 + r;
    pb[32 + rowq * HD + w * 32 + li] = Ov0[r];
    pb[32 + rowq * HD + w * 32 + 16 + li] = Ov1[r];
  }
}

// ---------------------------------------------------------------------------
// Combine 17 chunk-partials per (b,h) -> normalized ctx (bf16, [B,S,D] layout)
// ---------------------------------------------------------------------------
__global__ __launch_bounds__(256)
void combine_k(const float* __restrict__ part, bf16_t* __restrict__ ctx) {
  const int bh = blockIdx.x;
  const int tid = threadIdx.x;
  const int s = tid >> 4, d0 = (tid & 15) * 8;
  const float* pb = part + (long)bh * NCH * PSTRIDE;
  float mv[NCH];
  float M = -1e30f;
#pragma unroll
  for (int c = 0; c < NCH; ++c) { mv[c] = pb[c * PSTRIDE + s]; M = fmaxf(M, mv[c]); }
  float L = 0.f;
  f32x4 a0 = {0.f, 0.f, 0.f, 0.f}, a1 = {0.f, 0.f, 0.f, 0.f};
#pragma unroll
  for (int c = 0; c < NCH; ++c) {
    float wc = __expf(mv[c] - M);
    L += wc * pb[c * PSTRIDE + 16 + s];
    const float* ob = pb + c * PSTRIDE + 32 + s * HD + d0;
    f32x4 o0 = *(const f32x4*)ob;
    f32x4 o1 = *(const f32x4*)(ob + 4);
#pragma unroll
    for (int i = 0; i < 4; ++i) { a0[i] += wc * o0[i]; a1[i] += wc * o1[i]; }
  }
  float inv = 1.f / L;
  const int b = bh >> 4, h = bh & 15;
  bf16_t* cp = ctx + (long)(b * 16 + s) * D_ + h * HD + d0;
#pragma unroll
  for (int i = 0; i < 4; ++i) {
    cp[i] = (bf16_t)(a0[i] * inv);
    cp[4 + i] = (bf16_t)(a1[i] * inv);
  }
}

// ---------------------------------------------------------------------------
extern "C" void kernel_launch(void* const* d_in, const int* in_sizes, int n_in,
                              void* d_out, int out_size, void* d_ws, size_t ws_size,
                              hipStream_t stream) {
  const float* x  = (const float*)d_in[0];
  const float* kc = (const float*)d_in[1];
  const float* vc = (const float*)d_in[2];
  const float* Wa = (const float*)d_in[3];
  const float* ba = (const float*)d_in[4];
  const float* Wp = (const float*)d_in[5];
  const float* bp = (const float*)d_in[6];

  float* outp  = (float*)d_out;                       // [8,16,2048]
  float* khout = outp + (long)B_ * S_ * D_;           // [8,16,4112,128]
  float* vhout = khout + (long)B_ * H_ * TL * HD;     // [8,16,4112,128]

  bf16_t* qws   = (bf16_t*)d_ws;                              // 512 KB
  bf16_t* ctxws = (bf16_t*)((char*)d_ws + 524288);            // 512 KB
  float*  part  = (float*)((char*)d_ws + 1048576);            // ~18.1 MB

  // K1: QKV projection (writes q->ws bf16, new k/v -> kh/vh tails fp32)
  gemm_k<false, 1><<<192, 256, 0, stream>>>(
      x, Wa, ba, qws, khout, vhout, nullptr, 3 * D_);
  // K2: fused KV copy + flash attention partials
  attn_k<<<128 * NCH, 256, 0, stream>>>(kc, vc, qws, khout, vhout, part);
  // K3: combine partials -> ctx (bf16)
  combine_k<<<128, 256, 0, stream>>>(part, ctxws);
  // K4: output projection
  gemm_k<true, 0><<<64, 256, 0, stream>>>(
      ctxws, Wp, bp, nullptr, nullptr, nullptr, outp, D_);
}

// Round 2
// 1015.056 us; speedup vs baseline: 1.1575x; 1.1575x over previous
//
#include <hip/hip_runtime.h>

typedef __bf16 bf16_t;
typedef bf16_t bf16x8 __attribute__((ext_vector_type(8)));
typedef float f32x4 __attribute__((ext_vector_type(4)));

#define B_    8
#define H_    16
#define S_    16
#define D_    2048
#define HD    128
#define CL    4096
#define TL    4112
#define NCH   17        // 16 cache chunks + 1 "new keys" chunk
#define CHUNK 256
#define PSTRIDE 2080    // per (bh,chunk) partial: m[16], l[16], O[16][128]
#define SCALE 0.08838834764831845f  // 1/sqrt(128)

__device__ inline f32x4 mfma16(bf16x8 a, bf16x8 b, f32x4 c) {
  return __builtin_amdgcn_mfma_f32_16x16x32_bf16(a, b, c, 0, 0, 0);
}

__device__ inline bf16x8 cvt8(f32x4 a, f32x4 b) {
  bf16x8 r;
  r[0] = (bf16_t)a[0]; r[1] = (bf16_t)a[1]; r[2] = (bf16_t)a[2]; r[3] = (bf16_t)a[3];
  r[4] = (bf16_t)b[0]; r[5] = (bf16_t)b[1]; r[6] = (bf16_t)b[2]; r[7] = (bf16_t)b[3];
  return r;
}

// ---------------------------------------------------------------------------
// GEMM: A[128 x 2048] @ W[2048 x N] + bias.
// MODE 1 (QKV): N=6144, A=x (fp32). cols 0..2047 -> q_ws (bf16);
//               2048..4095 -> kh tail (fp32); 4096..6143 -> vh tail (fp32).
// MODE 0 (proj): N=2048, A=ctx (bf16). -> out (fp32).
// 256 thr = 4 waves; block tile 64 rows x 64 cols; wave tile 16x64.
// Double-buffered LDS + 2-deep register prefetch: one barrier per 32-k step,
// W loads always >=1 full iteration in flight. Grid is linear; blocks bid and
// bid+8 share a W column tile (same XCD under round-robin -> L2 hit).
// ---------------------------------------------------------------------------
template <bool ABF16, int MODE>
__global__ __launch_bounds__(256)
void gemm_k(const void* __restrict__ Ap_, const float* __restrict__ W,
            const float* __restrict__ bias, bf16_t* __restrict__ qout,
            float* __restrict__ khout, float* __restrict__ vhout,
            float* __restrict__ outp, int N) {
  __shared__ __align__(16) bf16_t Wt[2][64][40];  // [buf][n][k], 80 B rows
  const int tid = threadIdx.x;
  const int w = tid >> 6, lane = tid & 63, q4 = lane >> 4, li = lane & 15;
  const int bid = blockIdx.x;
  const int colb = (bid >> 4) * 8 + (bid & 7);   // column tile
  const int rowg = (bid >> 3) & 1;               // row group; partner is bid^8
  const int n0 = colb * 64;
  const int row = rowg * 64 + w * 16 + li;

  const int kk_a = tid >> 4, nn4 = (tid & 15) * 4;  // staging coords
  const long strideW = (long)32 * N;
  const float* Wpa = W + (long)kk_a * N + n0 + nn4;  // tile-row kk_a
  const float* Wpb = Wpa + (long)16 * N;             // tile-row kk_a+16

  f32x4 acc[4];
#pragma unroll
  for (int i = 0; i < 4; ++i) acc[i] = (f32x4){0.f, 0.f, 0.f, 0.f};

  const bf16_t* Ab = (const bf16_t*)Ap_ + (long)row * D_;
  const float* Af = (const float*)Ap_ + (long)row * D_;

  // W prefetch: tile0 -> a-regs (staged immediately), tile1 -> b-regs
  f32x4 wa0 = *(const f32x4*)Wpa;
  f32x4 wa1 = *(const f32x4*)Wpb;
  f32x4 wb0 = *(const f32x4*)(Wpa + strideW);
  f32x4 wb1 = *(const f32x4*)(Wpb + strideW);
  // A prefetch for t=0
  bf16x8 aCb = {};
  f32x4 aC0 = {0.f, 0.f, 0.f, 0.f}, aC1 = {0.f, 0.f, 0.f, 0.f};
  if (ABF16) aCb = *(const bf16x8*)(Ab + q4 * 8);
  else { aC0 = *(const f32x4*)(Af + q4 * 8); aC1 = *(const f32x4*)(Af + q4 * 8 + 4); }

#pragma unroll
  for (int i = 0; i < 4; ++i) {
    Wt[0][nn4 + i][kk_a] = (bf16_t)wa0[i];
    Wt[0][nn4 + i][kk_a + 16] = (bf16_t)wa1[i];
  }
  __syncthreads();

#pragma unroll 2
  for (int t = 0; t < 64; ++t) {
    const int cur = t & 1;
    const int k0 = t * 32;
    // prefetch W tile t+2 into n-regs
    f32x4 na0 = {0.f, 0.f, 0.f, 0.f}, na1 = {0.f, 0.f, 0.f, 0.f};
    if (t < 62) {
      na0 = *(const f32x4*)(Wpa + (long)(t + 2) * strideW);
      na1 = *(const f32x4*)(Wpb + (long)(t + 2) * strideW);
    }
    // prefetch A for t+1
    bf16x8 aNb = {};
    f32x4 aN0 = {0.f, 0.f, 0.f, 0.f}, aN1 = {0.f, 0.f, 0.f, 0.f};
    if (t < 63) {
      if (ABF16) {
        aNb = *(const bf16x8*)(Ab + k0 + 32 + q4 * 8);
      } else {
        const float* ap = Af + k0 + 32 + q4 * 8;
        aN0 = *(const f32x4*)ap;
        aN1 = *(const f32x4*)(ap + 4);
      }
    }
    // compute tile t from Wt[cur]
    bf16x8 av;
    if (ABF16) av = aCb; else av = cvt8(aC0, aC1);
#pragma unroll
    for (int cg = 0; cg < 4; ++cg) {
      bf16x8 bv = *(const bf16x8*)(&Wt[cur][cg * 16 + li][q4 * 8]);
      acc[cg] = mfma16(av, bv, acc[cg]);
    }
    // stage tile t+1 (b-regs) -> other buffer
    if (t < 63) {
#pragma unroll
      for (int i = 0; i < 4; ++i) {
        Wt[cur ^ 1][nn4 + i][kk_a] = (bf16_t)wb0[i];
        Wt[cur ^ 1][nn4 + i][kk_a + 16] = (bf16_t)wb1[i];
      }
    }
    __syncthreads();
    if (t < 62) { wb0 = na0; wb1 = na1; }
    if (t < 63) { if (ABF16) aCb = aNb; else { aC0 = aN0; aC1 = aN1; } }
  }

#pragma unroll
  for (int cg = 0; cg < 4; ++cg) {
#pragma unroll
    for (int r = 0; r < 4; ++r) {
      int rr = rowg * 64 + w * 16 + q4 * 4 + r;  // C row = quad*4+reg
      int n = n0 + cg * 16 + li;                 // C col = lane&15
      float v = acc[cg][r] + bias[n];
      if (MODE == 0) {
        outp[(long)rr * D_ + n] = v;
      } else {
        if (n < D_) {
          qout[(long)rr * D_ + n] = (bf16_t)v;
        } else {
          int nn = n & (D_ - 1);
          int hh = nn >> 7, dd = nn & 127;
          int bb = rr >> 4, ss = rr & 15;
          long off = ((long)(bb * 16 + hh) * TL + CL + ss) * HD + dd;
          if (n < 2 * D_) khout[off] = v; else vhout[off] = v;
        }
      }
    }
  }
}

// ---------------------------------------------------------------------------
// Fused KV-copy + flash attention partials.
// Grid: 128 (b,h) x 17 chunks. Cache chunk = 256 keys (4 subtiles of 64);
// chunk 16 = the 16 new keys from the QKV GEMM. K loads double as the copy
// AND the QK B-frags. V is staged to LDS TRANSPOSED during the copy
// (Vt[d][t], 132-B rows: conflict-free u16 writes, 4B-aligned dword reads
// give the PV B-frags directly) -- no global V re-gather.
// kh/vh copy uses PLAIN stores: the wave scatters 16B chunks across 16 rows,
// so full 128B lines are only assembled in L2 write-combining. Non-temporal
// stores here caused partial-line RMW at HBM (WRITE_SIZE 1.02GB vs 575MB
// ideal, attn 427us) -- measured round 1, do not reintroduce.
// Softmax state m/l lives in registers replicated across (w,li); barriers:
// Bstart (LDS reuse guard), B1 (maxw+Vt ready), B3 (Pbuf+sumw ready).
// ---------------------------------------------------------------------------
__global__ __launch_bounds__(256)
void attn_k(const float* __restrict__ kc, const float* __restrict__ vc,
            const bf16_t* __restrict__ qw, float* __restrict__ khout,
            float* __restrict__ vhout, float* __restrict__ part) {
  const int blk = blockIdx.x;
  const int bh = blk / NCH, ch = blk - bh * NCH;
  const bool is_new = (ch == 16);
  const int tid = threadIdx.x;
  const int w = tid >> 6, lane = tid & 63, q4 = lane >> 4, li = lane & 15;
  const int b = bh >> 4, h = bh & 15;

  __shared__ float maxw[4][16], sumw[4][16];
  __shared__ __align__(16) bf16_t Pbuf[16][72];   // 144 B rows
  __shared__ __align__(16) bf16_t Vt[128][66];    // [d][t], 132 B rows

  // Q A-frags: lane holds Q[s=li][k0 + quad*8 + j]
  bf16x8 Aq[4];
  {
    const bf16_t* qp = qw + (long)(b * 16 + li) * D_ + h * HD + q4 * 8;
#pragma unroll
    for (int i = 0; i < 4; ++i) Aq[i] = *(const bf16x8*)(qp + i * 32);
  }
  f32x4 Ov0 = {0.f, 0.f, 0.f, 0.f}, Ov1 = {0.f, 0.f, 0.f, 0.f};
  float mreg[4], lreg[4];
#pragma unroll
  for (int r = 0; r < 4; ++r) { mreg[r] = -1e30f; lreg[r] = 0.f; }

  const int nst = is_new ? 1 : 4;
  for (int st = 0; st < nst; ++st) {
    const int tl_loc = w * 16 + li;      // key row local to subtile
    const int tloc = st * 64 + tl_loc;   // chunk-local key row

    __syncthreads();  // Bstart: previous subtile's Vt/Pbuf/maxw reads done

    // ---- K load (copy + B-frag), V copy + LDS transpose stage ----
    bf16x8 Bk[4];
    if (!is_new) {
      const float* kp = kc + ((long)bh * CL + ch * CHUNK + tloc) * HD;
      float* kq = khout + ((long)bh * TL + ch * CHUNK + tloc) * HD;
      const float* vp = vc + ((long)bh * CL + ch * CHUNK + tloc) * HD;
      float* vq = vhout + ((long)bh * TL + ch * CHUNK + tloc) * HD;
#pragma unroll
      for (int i = 0; i < 4; ++i) {
        int d0 = i * 32 + q4 * 8;
        f32x4 x0 = *(const f32x4*)(kp + d0);
        f32x4 x1 = *(const f32x4*)(kp + d0 + 4);
        *(f32x4*)(kq + d0) = x0;
        *(f32x4*)(kq + d0 + 4) = x1;
        Bk[i] = cvt8(x0, x1);
        f32x4 y0 = *(const f32x4*)(vp + d0);
        f32x4 y1 = *(const f32x4*)(vp + d0 + 4);
        *(f32x4*)(vq + d0) = y0;
        *(f32x4*)(vq + d0 + 4) = y1;
#pragma unroll
        for (int j = 0; j < 4; ++j) {
          Vt[d0 + j][tl_loc] = (bf16_t)y0[j];
          Vt[d0 + 4 + j][tl_loc] = (bf16_t)y1[j];
        }
      }
    } else {
      const bool valid = tloc < S_;
      const float* kp = khout + ((long)bh * TL + CL + tloc) * HD;
#pragma unroll
      for (int i = 0; i < 4; ++i) {
        int d0 = i * 32 + q4 * 8;
        f32x4 x0 = {0.f, 0.f, 0.f, 0.f}, x1 = {0.f, 0.f, 0.f, 0.f};
        if (valid) { x0 = *(const f32x4*)(kp + d0); x1 = *(const f32x4*)(kp + d0 + 4); }
        Bk[i] = cvt8(x0, x1);
      }
    }

    // ---- QK^T (wave's 16-key group), scale, mask ----
    f32x4 c = {0.f, 0.f, 0.f, 0.f};
#pragma unroll
    for (int i = 0; i < 4; ++i) c = mfma16(Aq[i], Bk[i], c);
    float sv[4];
#pragma unroll
    for (int r = 0; r < 4; ++r) {
      float v = c[r] * SCALE;
      if (is_new) {
        int rowq = q4 * 4 + r;
        if (tl_loc > rowq) v = -1e30f;  // causal
      }
      sv[r] = v;
    }

    // ---- wave-local row max over the 16 key-cols (lanes of a quad) ----
#pragma unroll
    for (int r = 0; r < 4; ++r) {
      float v = sv[r];
      v = fmaxf(v, __shfl_xor(v, 1));
      v = fmaxf(v, __shfl_xor(v, 2));
      v = fmaxf(v, __shfl_xor(v, 4));
      v = fmaxf(v, __shfl_xor(v, 8));
      if (li == 0) maxw[w][q4 * 4 + r] = v;
    }
    __syncthreads();  // B1: maxw + Vt ready

    // ---- replicated m-update, P = exp(S-m), Pbuf write ----
    float alpha[4], pv[4];
#pragma unroll
    for (int r = 0; r < 4; ++r) {
      int rowq = q4 * 4 + r;
      float mw = fmaxf(fmaxf(maxw[0][rowq], maxw[1][rowq]),
                       fmaxf(maxw[2][rowq], maxw[3][rowq]));
      float mn = fmaxf(mreg[r], mw);
      alpha[r] = __expf(mreg[r] - mn);
      mreg[r] = mn;
      float p = __expf(sv[r] - mn);
      pv[r] = p;
      Pbuf[rowq][tl_loc] = (bf16_t)p;
    }
#pragma unroll
    for (int r = 0; r < 4; ++r) {
      float u = pv[r];
      u += __shfl_xor(u, 1);
      u += __shfl_xor(u, 2);
      u += __shfl_xor(u, 4);
      u += __shfl_xor(u, 8);
      if (li == 0) sumw[w][q4 * 4 + r] = u;
    }
#pragma unroll
    for (int r = 0; r < 4; ++r) { Ov0[r] *= alpha[r]; Ov1[r] *= alpha[r]; }
    __syncthreads();  // B3: Pbuf + sumw ready

#pragma unroll
    for (int r = 0; r < 4; ++r) {
      int rowq = q4 * 4 + r;
      lreg[r] = lreg[r] * alpha[r] +
                sumw[0][rowq] + sumw[1][rowq] + sumw[2][rowq] + sumw[3][rowq];
    }

    // ---- V B-frags: from Vt (dword reads, 4B-aligned) ----
    bf16x8 Bv[2][2];
    if (!is_new) {
#pragma unroll
      for (int kst = 0; kst < 2; ++kst)
#pragma unroll
        for (int cg = 0; cg < 2; ++cg) {
          int d = w * 32 + cg * 16 + li;
          const unsigned int* vr =
              (const unsigned int*)&Vt[d][kst * 32 + q4 * 8];
          union { unsigned int u[4]; bf16x8 v; } tmp;
          tmp.u[0] = vr[0]; tmp.u[1] = vr[1]; tmp.u[2] = vr[2]; tmp.u[3] = vr[3];
          Bv[kst][cg] = tmp.v;
        }
    } else {
      const float* vb = vhout + ((long)bh * TL + CL) * HD;
#pragma unroll
      for (int kst = 0; kst < 2; ++kst)
#pragma unroll
        for (int cg = 0; cg < 2; ++cg) {
          int d = w * 32 + cg * 16 + li;
#pragma unroll
          for (int j = 0; j < 8; ++j) {
            int tl = kst * 32 + q4 * 8 + j;
            float v = (tl < S_) ? vb[(long)tl * HD + d] : 0.f;
            Bv[kst][cg][j] = (bf16_t)v;
          }
        }
    }

    // ---- PV: A-frags of P from LDS, accumulate O ----
    bf16x8 Ap0 = *(const bf16x8*)(&Pbuf[li][q4 * 8]);
    bf16x8 Ap1 = *(const bf16x8*)(&Pbuf[li][32 + q4 * 8]);
    Ov0 = mfma16(Ap0, Bv[0][0], Ov0);
    Ov0 = mfma16(Ap1, Bv[1][0], Ov0);
    Ov1 = mfma16(Ap0, Bv[0][1], Ov1);
    Ov1 = mfma16(Ap1, Bv[1][1], Ov1);
  }

  // ---- write chunk partial: m[16], l[16], O[16][128] ----
  float* pb = part + ((long)bh * NCH + ch) * PSTRIDE;
  if (w == 0 && li == 0) {
#pragma unroll
    for (int r = 0; r < 4; ++r) {
      pb[q4 * 4 + r] = mreg[r];
      pb[16 + q4 * 4 + r] = lreg[r];
    }
  }
#pragma unroll
  for (int r = 0; r < 4; ++r) {
    int rowq = q4 * 4 + r;
    pb[32 + rowq * HD + w * 32 + li] = Ov0[r];
    pb[32 + rowq * HD + w * 32 + 16 + li] = Ov1[r];
  }
}

// ---------------------------------------------------------------------------
// Combine 17 chunk-partials per (b,h) -> normalized ctx (bf16, [B,S,D] layout)
// ---------------------------------------------------------------------------
__global__ __launch_bounds__(256)
void combine_k(const float* __restrict__ part, bf16_t* __restrict__ ctx) {
  const int bh = blockIdx.x;
  const int tid = threadIdx.x;
  const int s = tid >> 4, d0 = (tid & 15) * 8;
  const float* pb = part + (long)bh * NCH * PSTRIDE;
  float mv[NCH];
  float M = -1e30f;
#pragma unroll
  for (int c = 0; c < NCH; ++c) { mv[c] = pb[c * PSTRIDE + s]; M = fmaxf(M, mv[c]); }
  float L = 0.f;
  f32x4 a0 = {0.f, 0.f, 0.f, 0.f}, a1 = {0.f, 0.f, 0.f, 0.f};
#pragma unroll
  for (int c = 0; c < NCH; ++c) {
    float wc = __expf(mv[c] - M);
    L += wc * pb[c * PSTRIDE + 16 + s];
    const float* ob = pb + c * PSTRIDE + 32 + s * HD + d0;
    f32x4 o0 = *(const f32x4*)ob;
    f32x4 o1 = *(const f32x4*)(ob + 4);
#pragma unroll
    for (int i = 0; i < 4; ++i) { a0[i] += wc * o0[i]; a1[i] += wc * o1[i]; }
  }
  float inv = 1.f / L;
  const int b = bh >> 4, h = bh & 15;
  bf16_t* cp = ctx + (long)(b * 16 + s) * D_ + h * HD + d0;
#pragma unroll
  for (int i = 0; i < 4; ++i) {
    cp[i] = (bf16_t)(a0[i] * inv);
    cp[4 + i] = (bf16_t)(a1[i] * inv);
  }
}

// ---------------------------------------------------------------------------
extern "C" void kernel_launch(void* const* d_in, const int* in_sizes, int n_in,
                              void* d_out, int out_size, void* d_ws, size_t ws_size,
                              hipStream_t stream) {
  const float* x  = (const float*)d_in[0];
  const float* kc = (const float*)d_in[1];
  const float* vc = (const float*)d_in[2];
  const float* Wa = (const float*)d_in[3];
  const float* ba = (const float*)d_in[4];
  const float* Wp = (const float*)d_in[5];
  const float* bp = (const float*)d_in[6];

  float* outp  = (float*)d_out;                       // [8,16,2048]
  float* khout = outp + (long)B_ * S_ * D_;           // [8,16,4112,128]
  float* vhout = khout + (long)B_ * H_ * TL * HD;     // [8,16,4112,128]

  bf16_t* qws   = (bf16_t*)d_ws;                              // 512 KB
  bf16_t* ctxws = (bf16_t*)((char*)d_ws + 524288);            // 512 KB
  float*  part  = (float*)((char*)d_ws + 1048576);            // ~18.1 MB

  // K1: QKV projection (writes q->ws bf16, new k/v -> kh/vh tails fp32)
  gemm_k<false, 1><<<192, 256, 0, stream>>>(
      x, Wa, ba, qws, khout, vhout, nullptr, 3 * D_);
  // K2: fused KV copy + flash attention partials
  attn_k<<<128 * NCH, 256, 0, stream>>>(kc, vc, qws, khout, vhout, part);
  // K3: combine partials -> ctx (bf16)
  combine_k<<<128, 256, 0, stream>>>(part, ctxws);
  // K4: output projection
  gemm_k<true, 0><<<64, 256, 0, stream>>>(
      ctxws, Wp, bp, nullptr, nullptr, nullptr, outp, D_);
}